// Round 2
// baseline (987.262 us; speedup 1.0000x reference)
//
#include <hip/hip_runtime.h>
#include <hip/hip_fp16.h>

static constexpr float KEHALF = 7.199822675975274f; // 14.399645351950548 / 2
static constexpr int NUM_XCD = 8;

typedef float v4f __attribute__((ext_vector_type(4)));
typedef int   v4i __attribute__((ext_vector_type(4)));

// ---------------------------------------------------------------------------
// XCD id (0..7) via HW_REG_XCC_ID (hwreg 20, offset 0, width 4).
// ---------------------------------------------------------------------------
__device__ __forceinline__ int xcd_id() {
    return (int)(__builtin_amdgcn_s_getreg((3u << 11) | (0u << 6) | 20u) & 7u);
}

// Atomic add WITHOUT sc bits: the RMW executes in the local XCD's L2
// (not forwarded memory-side). Only valid because each XCD owns a private
// partial array — cross-XCD visibility happens at end-of-dispatch writeback.
__device__ __forceinline__ void atomic_add_xcd_l2(float* p, float v) {
    asm volatile("global_atomic_add_f32 %0, %1, off"
                 :: "v"((unsigned long long)(uintptr_t)p), "v"(v)
                 : "memory");
}

// ---------------------------------------------------------------------------
// Kernel 1: softplus'd constants.
// consts: [0]=sp(apow) [1]=sp(adiv) [2..5]=c1n..c4n [6..9]=sp(a1..a4)
// ---------------------------------------------------------------------------
__global__ void zbl_consts_kernel(const float* __restrict__ adiv,
                                  const float* __restrict__ apow,
                                  const float* __restrict__ c1,
                                  const float* __restrict__ c2,
                                  const float* __restrict__ c3,
                                  const float* __restrict__ c4,
                                  const float* __restrict__ a1,
                                  const float* __restrict__ a2,
                                  const float* __restrict__ a3,
                                  const float* __restrict__ a4,
                                  float* __restrict__ consts) {
    if (threadIdx.x == 0 && blockIdx.x == 0) {
        auto sp = [](float x) { return log1pf(expf(x)); };
        float c1p = sp(*c1), c2p = sp(*c2), c3p = sp(*c3), c4p = sp(*c4);
        float inv = 1.0f / (c1p + c2p + c3p + c4p);
        consts[0] = sp(*apow);
        consts[1] = sp(*adiv);
        consts[2] = c1p * inv;
        consts[3] = c2p * inv;
        consts[4] = c3p * inv;
        consts[5] = c4p * inv;
        consts[6] = sp(*a1);
        consts[7] = sp(*a2);
        consts[8] = sp(*a3);
        consts[9] = sp(*a4);
    }
}

// ---------------------------------------------------------------------------
// Kernel 2: packed per-atom table  packed[i] = (half)Zf[i], (half)Zf[i]^sp(apow)
// 2 MB total -> L2-resident; one 4 B gather per pair side instead of two.
// Zf (1..94) is exact in half; z in half is 0.05% rel err.
// ---------------------------------------------------------------------------
__global__ void zbl_pack_kernel(const float* __restrict__ Zf,
                                const float* __restrict__ consts,
                                __half2* __restrict__ packed, int N) {
    int i = blockIdx.x * blockDim.x + threadIdx.x;
    if (i < N) {
        float zf = Zf[i];
        float z = powf(zf, consts[0]);
        packed[i] = __halves2half2(__float2half_rn(zf), __float2half_rn(z));
    }
}

// ---------------------------------------------------------------------------
// Kernel 3: per-pair energy, 4 pairs/thread, nontemporal stream loads,
// XCD-L2-local atomics into the per-XCD partial.
// ---------------------------------------------------------------------------
__global__ void __launch_bounds__(256)
zbl_pair_kernel(const v4f* __restrict__ rij4,
                const v4f* __restrict__ cut4,
                const v4i* __restrict__ ii4,
                const v4i* __restrict__ jj4,
                const __half2* __restrict__ packed,
                const float* __restrict__ consts,
                float* __restrict__ partials,
                int N, int P4) {
    int t = blockIdx.x * blockDim.x + threadIdx.x;
    if (t >= P4) return;

    const float sp_adiv = consts[1];
    const float c1n = consts[2], c2n = consts[3], c3n = consts[4], c4n = consts[5];
    const float a1 = consts[6], a2 = consts[7], a3 = consts[8], a4 = consts[9];

    float* mypart = partials + (size_t)xcd_id() * (size_t)N;

    v4f r4 = __builtin_nontemporal_load(rij4 + t);
    v4f c4 = __builtin_nontemporal_load(cut4 + t);
    v4i i4 = __builtin_nontemporal_load(ii4 + t);
    v4i j4 = __builtin_nontemporal_load(jj4 + t);

#pragma unroll
    for (int k = 0; k < 4; ++k) {
        int i = i4[k], j = j4[k];
        float r = r4[k];
        float cut = c4[k];
        float2 pi = __half22float2(packed[i]);   // x=Zf, y=z
        float2 pj = __half22float2(packed[j]);
        float a = (pi.y + pj.y) * sp_adiv;
        float ar = a * r;
        float f = c1n * __expf(-a1 * ar)
                + c2n * __expf(-a2 * ar)
                + c3n * __expf(-a3 * ar)
                + c4n * __expf(-a4 * ar);
        float zizj = pi.x * pj.x;
        float contrib = KEHALF * f * cut * zizj * __builtin_amdgcn_rcpf(r);
        atomic_add_xcd_l2(&mypart[i], contrib);
    }
}

// ---------------------------------------------------------------------------
// Kernel 4: out[i] = sum over 8 XCD partials. Vectorized x4.
// ---------------------------------------------------------------------------
__global__ void zbl_reduce_kernel(const float* __restrict__ partials,
                                  float* __restrict__ out, int N, int N4) {
    int t = blockIdx.x * blockDim.x + threadIdx.x;
    if (t < N4) {
        v4f s = {0.f, 0.f, 0.f, 0.f};
#pragma unroll
        for (int k = 0; k < NUM_XCD; ++k) {
            v4f p = *reinterpret_cast<const v4f*>(partials + (size_t)k * N + 4 * t);
            s += p;
        }
        *reinterpret_cast<v4f*>(out + 4 * t) = s;
    } else {
        int idx = 4 * N4 + (t - N4);
        if (idx < N) {
            float s = 0.f;
#pragma unroll
            for (int k = 0; k < NUM_XCD; ++k) s += partials[(size_t)k * N + idx];
            out[idx] = s;
        }
    }
}

// ---------------------------------------------------------------------------
// Fallback (ws too small): direct device-scope atomics into out.
// ---------------------------------------------------------------------------
__global__ void __launch_bounds__(256)
zbl_pair_fallback(const v4f* __restrict__ rij4, const v4f* __restrict__ cut4,
                  const v4i* __restrict__ ii4, const v4i* __restrict__ jj4,
                  const float* __restrict__ Zf, const float* __restrict__ consts,
                  float* __restrict__ out, int P4) {
    int t = blockIdx.x * blockDim.x + threadIdx.x;
    if (t >= P4) return;
    const float sp_apow = consts[0], sp_adiv = consts[1];
    const float c1n = consts[2], c2n = consts[3], c3n = consts[4], c4n = consts[5];
    const float a1 = consts[6], a2 = consts[7], a3 = consts[8], a4 = consts[9];
    v4f r4 = rij4[t]; v4f c4 = cut4[t]; v4i i4 = ii4[t]; v4i j4 = jj4[t];
#pragma unroll
    for (int k = 0; k < 4; ++k) {
        int i = i4[k], j = j4[k];
        float zi = Zf[i], zj = Zf[j];
        float a = (powf(zi, sp_apow) + powf(zj, sp_apow)) * sp_adiv;
        float ar = a * r4[k];
        float f = c1n * __expf(-a1 * ar) + c2n * __expf(-a2 * ar)
                + c3n * __expf(-a3 * ar) + c4n * __expf(-a4 * ar);
        atomicAdd(&out[i], KEHALF * f * c4[k] * zi * zj * __builtin_amdgcn_rcpf(r4[k]));
    }
}

// ---------------------------------------------------------------------------
extern "C" void kernel_launch(void* const* d_in, const int* in_sizes, int n_in,
                              void* d_out, int out_size, void* d_ws, size_t ws_size,
                              hipStream_t stream) {
    // 0:N 1:Zf 2:rij 3:cutoff 4:idx_i 5:idx_j 6:adiv 7:apow 8..11:c1..c4 12..15:a1..a4
    const float* Zf = (const float*)d_in[1];
    const float* rij = (const float*)d_in[2];
    const float* cut = (const float*)d_in[3];
    const int* idx_i = (const int*)d_in[4];
    const int* idx_j = (const int*)d_in[5];

    const int N = in_sizes[1];
    const int P = in_sizes[2];
    const int P4 = P / 4;
    float* out = (float*)d_out;

    // ws layout: partials[8*N] | packed[N] half2 | consts[10]
    size_t need = (size_t)NUM_XCD * N * 4 + (size_t)N * 4 + 64;
    if (ws_size < need) {
        float* consts = (float*)d_ws;
        hipMemsetAsync(out, 0, (size_t)out_size * sizeof(float), stream);
        zbl_consts_kernel<<<1, 64, 0, stream>>>(
            (const float*)d_in[6], (const float*)d_in[7],
            (const float*)d_in[8], (const float*)d_in[9],
            (const float*)d_in[10], (const float*)d_in[11],
            (const float*)d_in[12], (const float*)d_in[13],
            (const float*)d_in[14], (const float*)d_in[15], consts);
        zbl_pair_fallback<<<(P4 + 255) / 256, 256, 0, stream>>>(
            (const v4f*)rij, (const v4f*)cut, (const v4i*)idx_i, (const v4i*)idx_j,
            Zf, consts, out, P4);
        return;
    }

    float* partials = (float*)d_ws;
    __half2* packed = (__half2*)(partials + (size_t)NUM_XCD * N);
    float* consts = (float*)(packed + N);

    // Zero the per-XCD partials (harness poisons ws with 0xAA each call).
    hipMemsetAsync(partials, 0, (size_t)NUM_XCD * N * sizeof(float), stream);

    zbl_consts_kernel<<<1, 64, 0, stream>>>(
        (const float*)d_in[6], (const float*)d_in[7],
        (const float*)d_in[8], (const float*)d_in[9],
        (const float*)d_in[10], (const float*)d_in[11],
        (const float*)d_in[12], (const float*)d_in[13],
        (const float*)d_in[14], (const float*)d_in[15], consts);

    zbl_pack_kernel<<<(N + 255) / 256, 256, 0, stream>>>(Zf, consts, packed, N);

    zbl_pair_kernel<<<(P4 + 255) / 256, 256, 0, stream>>>(
        (const v4f*)rij, (const v4f*)cut, (const v4i*)idx_i, (const v4i*)idx_j,
        packed, consts, partials, N, P4);

    const int N4 = N / 4;
    const int tail = N - 4 * N4;
    zbl_reduce_kernel<<<(N4 + tail + 255) / 256, 256, 0, stream>>>(partials, out, N, N4);
}

// Round 3
// 844.123 us; speedup vs baseline: 1.1696x; 1.1696x over previous
//
#include <hip/hip_runtime.h>
#include <hip/hip_fp16.h>

static constexpr float KEHALF = 7.199822675975274f; // 14.399645351950548 / 2
static constexpr int APB = 2048;          // atoms per bucket (8 KB LDS tile)
static constexpr int APB_SHIFT = 11;
static constexpr int NB_MAX = 512;        // max buckets supported
static constexpr int CHUNK = 16384;       // pairs per Phase-A block
static constexpr int ABLK = 256;          // Phase-A block size
static constexpr int BBLK = 1024;         // Phase-B block size

typedef float v4f __attribute__((ext_vector_type(4)));
typedef int   v4i __attribute__((ext_vector_type(4)));

// ---------------------------------------------------------------------------
// Record encodings.
//  Rec8: 8 B = [idx_local:32 | f32 contrib bits:32]  (full precision)
//  Rec4: 4 B = [idx_local:16 | bf16 contrib:16]      (0.2% rel, still << thr)
// ---------------------------------------------------------------------------
__device__ __forceinline__ unsigned f2bf_rne(float f) {
    unsigned u = __float_as_uint(f);
    return ((u + 0x7fffu + ((u >> 16) & 1u)) >> 16) & 0xffffu;
}
struct Rec8 {
    typedef unsigned long long T;
    static __device__ __forceinline__ T enc(unsigned il, float v) {
        return ((T)il << 32) | (T)__float_as_uint(v);
    }
    static __device__ __forceinline__ unsigned idx(T r) { return (unsigned)(r >> 32); }
    static __device__ __forceinline__ float val(T r) { return __uint_as_float((unsigned)r); }
};
struct Rec4 {
    typedef unsigned T;
    static __device__ __forceinline__ T enc(unsigned il, float v) {
        return (il << 16) | f2bf_rne(v);
    }
    static __device__ __forceinline__ unsigned idx(T r) { return r >> 16; }
    static __device__ __forceinline__ float val(T r) { return __uint_as_float(r << 16); }
};

// ---------------------------------------------------------------------------
// consts: [0]=sp(apow) [1]=sp(adiv) [2..5]=c1n..c4n [6..9]=sp(a1..a4)
// ---------------------------------------------------------------------------
__global__ void zbl_consts_kernel(const float* __restrict__ adiv,
                                  const float* __restrict__ apow,
                                  const float* __restrict__ c1,
                                  const float* __restrict__ c2,
                                  const float* __restrict__ c3,
                                  const float* __restrict__ c4,
                                  const float* __restrict__ a1,
                                  const float* __restrict__ a2,
                                  const float* __restrict__ a3,
                                  const float* __restrict__ a4,
                                  float* __restrict__ consts) {
    if (threadIdx.x == 0 && blockIdx.x == 0) {
        auto sp = [](float x) { return log1pf(expf(x)); };
        float c1p = sp(*c1), c2p = sp(*c2), c3p = sp(*c3), c4p = sp(*c4);
        float inv = 1.0f / (c1p + c2p + c3p + c4p);
        consts[0] = sp(*apow);
        consts[1] = sp(*adiv);
        consts[2] = c1p * inv; consts[3] = c2p * inv;
        consts[4] = c3p * inv; consts[5] = c4p * inv;
        consts[6] = sp(*a1); consts[7] = sp(*a2);
        consts[8] = sp(*a3); consts[9] = sp(*a4);
    }
}

// ---------------------------------------------------------------------------
// packed[i] = (half)Zf[i], (half)Zf[i]^sp(apow) — 2 MB L2-resident gather table
// ---------------------------------------------------------------------------
__global__ void zbl_pack_kernel(const float* __restrict__ Zf,
                                const float* __restrict__ consts,
                                __half2* __restrict__ packed, int N) {
    int i = blockIdx.x * blockDim.x + threadIdx.x;
    if (i < N) {
        float zf = Zf[i];
        float z = powf(zf, consts[0]);
        packed[i] = __halves2half2(__float2half_rn(zf), __float2half_rn(z));
    }
}

// ---------------------------------------------------------------------------
// Global bucket histogram of idx_i (exact counts; ~240K global atomics total)
// ---------------------------------------------------------------------------
__global__ void __launch_bounds__(256)
zbl_hist_kernel(const v4i* __restrict__ idx_i4, unsigned* __restrict__ ghist,
                int P, int NB) {
    __shared__ unsigned hist[NB_MAX];
    int t = threadIdx.x;
    for (int b = t; b < NB; b += 256) hist[b] = 0;
    __syncthreads();
    int P4 = P >> 2;
    for (int q = blockIdx.x * 256 + t; q < P4; q += gridDim.x * 256) {
        v4i ii = __builtin_nontemporal_load(idx_i4 + q);
        atomicAdd(&hist[(unsigned)ii[0] >> APB_SHIFT], 1u);
        atomicAdd(&hist[(unsigned)ii[1] >> APB_SHIFT], 1u);
        atomicAdd(&hist[(unsigned)ii[2] >> APB_SHIFT], 1u);
        atomicAdd(&hist[(unsigned)ii[3] >> APB_SHIFT], 1u);
    }
    if (blockIdx.x == 0 && t == 0) {
        const int* ii = reinterpret_cast<const int*>(idx_i4);
        for (int p = P4 * 4; p < P; ++p)
            atomicAdd(&hist[(unsigned)ii[p] >> APB_SHIFT], 1u);
    }
    __syncthreads();
    for (int b = t; b < NB; b += 256)
        if (hist[b]) atomicAdd(&ghist[b], hist[b]);
}

// ---------------------------------------------------------------------------
// Serial exclusive scan (NB <= 512, trivial) -> start[], tail init
// ---------------------------------------------------------------------------
__global__ void zbl_scan_kernel(const unsigned* __restrict__ ghist,
                                unsigned* __restrict__ start,
                                unsigned* __restrict__ tail, int NB) {
    if (threadIdx.x == 0 && blockIdx.x == 0) {
        unsigned s = 0;
        for (int b = 0; b < NB; ++b) {
            start[b] = s; tail[b] = s; s += ghist[b];
        }
        start[NB] = s;
    }
}

// ---------------------------------------------------------------------------
// Phase A: per-chunk LDS histogram -> one tail atomic per (block,bucket) ->
// compute contribs -> dense record scatter (plain stores, no hot atomics)
// ---------------------------------------------------------------------------
template <class R>
__global__ void __launch_bounds__(ABLK)
zbl_phaseA(const v4i* __restrict__ idx_i4, const v4i* __restrict__ idx_j4,
           const v4f* __restrict__ rij4, const v4f* __restrict__ cut4,
           const __half2* __restrict__ packed, const float* __restrict__ consts,
           unsigned* __restrict__ tail, typename R::T* __restrict__ recs,
           int P, int NB) {
    __shared__ unsigned hist[NB_MAX];
    __shared__ unsigned baseo[NB_MAX];
    __shared__ unsigned cursor[NB_MAX];
    const int t = threadIdx.x;
    for (int b = t; b < NB; b += ABLK) { hist[b] = 0; cursor[b] = 0; }
    __syncthreads();

    const int P4 = P >> 2;
    const int base4 = blockIdx.x * (CHUNK / 4);
    const bool lastblk = (blockIdx.x == gridDim.x - 1);

    // ---- pass 1: local histogram of this chunk
    for (int it = 0; it < CHUNK / 4 / ABLK; ++it) {
        int q = base4 + it * ABLK + t;
        if (q < P4) {
            v4i ii = __builtin_nontemporal_load(idx_i4 + q);
            atomicAdd(&hist[(unsigned)ii[0] >> APB_SHIFT], 1u);
            atomicAdd(&hist[(unsigned)ii[1] >> APB_SHIFT], 1u);
            atomicAdd(&hist[(unsigned)ii[2] >> APB_SHIFT], 1u);
            atomicAdd(&hist[(unsigned)ii[3] >> APB_SHIFT], 1u);
        }
    }
    if (lastblk && t == 0) {
        const int* ii = reinterpret_cast<const int*>(idx_i4);
        for (int p = P4 * 4; p < P; ++p)
            atomicAdd(&hist[(unsigned)ii[p] >> APB_SHIFT], 1u);
    }
    __syncthreads();

    // ---- reserve dense ranges (one global atomic per nonempty bucket)
    for (int b = t; b < NB; b += ABLK) {
        unsigned c = hist[b];
        baseo[b] = c ? atomicAdd(&tail[b], c) : 0u;
    }
    __syncthreads();

    // ---- pass 2: compute + scatter records
    const float sp_adiv = consts[1];
    const float c1n = consts[2], c2n = consts[3], c3n = consts[4], c4n = consts[5];
    const float a1 = consts[6], a2 = consts[7], a3 = consts[8], a4 = consts[9];

    for (int it = 0; it < CHUNK / 4 / ABLK; ++it) {
        int q = base4 + it * ABLK + t;
        if (q < P4) {
            v4i ii = __builtin_nontemporal_load(idx_i4 + q);
            v4i jj = __builtin_nontemporal_load(idx_j4 + q);
            v4f rr = __builtin_nontemporal_load(rij4 + q);
            v4f cc = __builtin_nontemporal_load(cut4 + q);
#pragma unroll
            for (int k = 0; k < 4; ++k) {
                int i = ii[k], j = jj[k];
                float r = rr[k];
                float2 pi = __half22float2(packed[i]);
                float2 pj = __half22float2(packed[j]);
                float a = (pi.y + pj.y) * sp_adiv;
                float ar = a * r;
                float f = c1n * __expf(-a1 * ar) + c2n * __expf(-a2 * ar)
                        + c3n * __expf(-a3 * ar) + c4n * __expf(-a4 * ar);
                float contrib = KEHALF * f * cc[k] * pi.x * pj.x *
                                __builtin_amdgcn_rcpf(r);
                unsigned b = (unsigned)i >> APB_SHIFT;
                unsigned rank = atomicAdd(&cursor[b], 1u);
                recs[baseo[b] + rank] = R::enc((unsigned)i & (APB - 1), contrib);
            }
        }
    }
    if (lastblk && t == 0) {
        const int* iig = reinterpret_cast<const int*>(idx_i4);
        const int* jjg = reinterpret_cast<const int*>(idx_j4);
        const float* rg = reinterpret_cast<const float*>(rij4);
        const float* cg = reinterpret_cast<const float*>(cut4);
        for (int p = P4 * 4; p < P; ++p) {
            int i = iig[p], j = jjg[p];
            float r = rg[p];
            float2 pi = __half22float2(packed[i]);
            float2 pj = __half22float2(packed[j]);
            float a = (pi.y + pj.y) * sp_adiv;
            float ar = a * r;
            float f = c1n * __expf(-a1 * ar) + c2n * __expf(-a2 * ar)
                    + c3n * __expf(-a3 * ar) + c4n * __expf(-a4 * ar);
            float contrib = KEHALF * f * cg[p] * pi.x * pj.x *
                            __builtin_amdgcn_rcpf(r);
            unsigned b = (unsigned)i >> APB_SHIFT;
            unsigned rank = atomicAdd(&cursor[b], 1u);
            recs[baseo[b] + rank] = R::enc((unsigned)i & (APB - 1), contrib);
        }
    }
}

// ---------------------------------------------------------------------------
// Phase B: one block per bucket — LDS accumulate, plain store. No atomics.
// ---------------------------------------------------------------------------
template <class R>
__global__ void __launch_bounds__(BBLK)
zbl_phaseB(const typename R::T* __restrict__ recs,
           const unsigned* __restrict__ start,
           float* __restrict__ out, int N) {
    __shared__ float acc[APB];
    const int t = threadIdx.x;
    const int b = blockIdx.x;
    for (int i = t; i < APB; i += BBLK) acc[i] = 0.f;
    __syncthreads();
    unsigned s = start[b], e = start[b + 1];
    unsigned u = s + t;
    for (; u + 3u * BBLK < e; u += 4u * BBLK) {
        typename R::T r0 = recs[u];
        typename R::T r1 = recs[u + BBLK];
        typename R::T r2 = recs[u + 2u * BBLK];
        typename R::T r3 = recs[u + 3u * BBLK];
        atomicAdd(&acc[R::idx(r0)], R::val(r0));
        atomicAdd(&acc[R::idx(r1)], R::val(r1));
        atomicAdd(&acc[R::idx(r2)], R::val(r2));
        atomicAdd(&acc[R::idx(r3)], R::val(r3));
    }
    for (; u < e; u += BBLK) {
        typename R::T r0 = recs[u];
        atomicAdd(&acc[R::idx(r0)], R::val(r0));
    }
    __syncthreads();
    int abase = b << APB_SHIFT;
    for (int i = t; i < APB; i += BBLK) {
        int g = abase + i;
        if (g < N) out[g] = acc[i];
    }
}

// ---------------------------------------------------------------------------
// Fallback: direct device-scope atomics (round-1/2 behavior)
// ---------------------------------------------------------------------------
__global__ void __launch_bounds__(256)
zbl_pair_fallback(const v4f* __restrict__ rij4, const v4f* __restrict__ cut4,
                  const v4i* __restrict__ ii4, const v4i* __restrict__ jj4,
                  const __half2* __restrict__ packed, const float* __restrict__ consts,
                  float* __restrict__ out, int P4) {
    int t = blockIdx.x * blockDim.x + threadIdx.x;
    if (t >= P4) return;
    const float sp_adiv = consts[1];
    const float c1n = consts[2], c2n = consts[3], c3n = consts[4], c4n = consts[5];
    const float a1 = consts[6], a2 = consts[7], a3 = consts[8], a4 = consts[9];
    v4f rr = rij4[t]; v4f cc = cut4[t]; v4i ii = ii4[t]; v4i jj = jj4[t];
#pragma unroll
    for (int k = 0; k < 4; ++k) {
        int i = ii[k], j = jj[k];
        float r = rr[k];
        float2 pi = __half22float2(packed[i]);
        float2 pj = __half22float2(packed[j]);
        float a = (pi.y + pj.y) * sp_adiv;
        float ar = a * r;
        float f = c1n * __expf(-a1 * ar) + c2n * __expf(-a2 * ar)
                + c3n * __expf(-a3 * ar) + c4n * __expf(-a4 * ar);
        atomicAdd(&out[i], KEHALF * f * cc[k] * pi.x * pj.x * __builtin_amdgcn_rcpf(r));
    }
}

// ---------------------------------------------------------------------------
template <class R>
static void launch_binned(const int* idx_i, const int* idx_j,
                          const float* rij, const float* cut,
                          const float* Zf,
                          void* const* d_in, void* d_ws,
                          float* out, int N, int P, int NB,
                          hipStream_t stream) {
    // ws layout: recs[P] | packed[N] half2 | consts[16] f32 | ghist | start | tail
    typename R::T* recs = (typename R::T*)d_ws;
    __half2* packed = (__half2*)(recs + P);
    float* consts = (float*)(packed + N);
    unsigned* ghist = (unsigned*)(consts + 16);
    unsigned* start = ghist + NB_MAX;
    unsigned* tail = start + NB_MAX + 1;

    hipMemsetAsync(ghist, 0, NB_MAX * sizeof(unsigned), stream);

    zbl_consts_kernel<<<1, 64, 0, stream>>>(
        (const float*)d_in[6], (const float*)d_in[7],
        (const float*)d_in[8], (const float*)d_in[9],
        (const float*)d_in[10], (const float*)d_in[11],
        (const float*)d_in[12], (const float*)d_in[13],
        (const float*)d_in[14], (const float*)d_in[15], consts);

    zbl_pack_kernel<<<(N + 255) / 256, 256, 0, stream>>>(Zf, consts, packed, N);

    zbl_hist_kernel<<<512, 256, 0, stream>>>((const v4i*)idx_i, ghist, P, NB);
    zbl_scan_kernel<<<1, 64, 0, stream>>>(ghist, start, tail, NB);

    int nblkA = (P + CHUNK - 1) / CHUNK;
    zbl_phaseA<R><<<nblkA, ABLK, 0, stream>>>(
        (const v4i*)idx_i, (const v4i*)idx_j, (const v4f*)rij, (const v4f*)cut,
        packed, consts, tail, recs, P, NB);

    zbl_phaseB<R><<<NB, BBLK, 0, stream>>>(recs, start, out, N);
}

extern "C" void kernel_launch(void* const* d_in, const int* in_sizes, int n_in,
                              void* d_out, int out_size, void* d_ws, size_t ws_size,
                              hipStream_t stream) {
    // 0:N 1:Zf 2:rij 3:cutoff 4:idx_i 5:idx_j 6:adiv 7:apow 8..11:c 12..15:a
    const float* Zf = (const float*)d_in[1];
    const float* rij = (const float*)d_in[2];
    const float* cut = (const float*)d_in[3];
    const int* idx_i = (const int*)d_in[4];
    const int* idx_j = (const int*)d_in[5];
    const int N = in_sizes[1];
    const int P = in_sizes[2];
    float* out = (float*)d_out;
    const int NB = (N + APB - 1) / APB;

    size_t fixed = (size_t)N * 4 + 64 * 4 + (3 * NB_MAX + 1) * 4 + 256;
    size_t need8 = (size_t)P * 8 + fixed;
    size_t need4 = (size_t)P * 4 + fixed;

    if (NB <= NB_MAX && ws_size >= need8) {
        launch_binned<Rec8>(idx_i, idx_j, rij, cut, Zf, d_in, d_ws, out, N, P, NB, stream);
    } else if (NB <= NB_MAX && ws_size >= need4) {
        launch_binned<Rec4>(idx_i, idx_j, rij, cut, Zf, d_in, d_ws, out, N, P, NB, stream);
    } else {
        // minimal-ws fallback: packed table + direct atomics
        __half2* packed = (__half2*)d_ws;
        float* consts = (float*)(packed + N);
        hipMemsetAsync(out, 0, (size_t)out_size * sizeof(float), stream);
        zbl_consts_kernel<<<1, 64, 0, stream>>>(
            (const float*)d_in[6], (const float*)d_in[7],
            (const float*)d_in[8], (const float*)d_in[9],
            (const float*)d_in[10], (const float*)d_in[11],
            (const float*)d_in[12], (const float*)d_in[13],
            (const float*)d_in[14], (const float*)d_in[15], consts);
        zbl_pack_kernel<<<(N + 255) / 256, 256, 0, stream>>>(Zf, consts, packed, N);
        zbl_pair_fallback<<<(P / 4 + 255) / 256, 256, 0, stream>>>(
            (const v4f*)rij, (const v4f*)cut, (const v4i*)idx_i, (const v4i*)idx_j,
            packed, consts, out, P / 4);
    }
}

// Round 4
// 531.335 us; speedup vs baseline: 1.8581x; 1.5887x over previous
//
#include <hip/hip_runtime.h>

static constexpr float KEHALF = 7.199822675975274f; // 14.399645351950548 / 2
static constexpr int APB = 2048;          // atoms per bucket (8 KB LDS tile)
static constexpr int APB_SHIFT = 11;
static constexpr int NBMAX = 256;         // scan width (pow2), NB must be <= this
static constexpr int CHUNK = 6144;        // pairs per Phase-A block (48 KB staging)
static constexpr int ABLK = 512;          // Phase-A block size
static constexpr int BBLK = 1024;         // Phase-B block size

typedef float v4f __attribute__((ext_vector_type(4)));
typedef int   v4i __attribute__((ext_vector_type(4)));
typedef unsigned long long u64;

// ---------------------------------------------------------------------------
// consts: [0]=sp(apow) [1]=sp(adiv) [2..5]=c1n..c4n [6..9]=sp(a1..a4)
// ---------------------------------------------------------------------------
__global__ void zbl_consts_kernel(const float* __restrict__ adiv,
                                  const float* __restrict__ apow,
                                  const float* __restrict__ c1,
                                  const float* __restrict__ c2,
                                  const float* __restrict__ c3,
                                  const float* __restrict__ c4,
                                  const float* __restrict__ a1,
                                  const float* __restrict__ a2,
                                  const float* __restrict__ a3,
                                  const float* __restrict__ a4,
                                  float* __restrict__ consts) {
    if (threadIdx.x == 0 && blockIdx.x == 0) {
        auto sp = [](float x) { return log1pf(expf(x)); };
        float c1p = sp(*c1), c2p = sp(*c2), c3p = sp(*c3), c4p = sp(*c4);
        float inv = 1.0f / (c1p + c2p + c3p + c4p);
        consts[0] = sp(*apow);
        consts[1] = sp(*adiv);
        consts[2] = c1p * inv; consts[3] = c2p * inv;
        consts[4] = c3p * inv; consts[5] = c4p * inv;
        consts[6] = sp(*a1); consts[7] = sp(*a2);
        consts[8] = sp(*a3); consts[9] = sp(*a4);
    }
}

// ---------------------------------------------------------------------------
// Phase A: per-chunk counting sort into LDS staging -> coalesced record flush.
// No global atomics anywhere. recs[c*CHUNK + localRank], bucket-grouped per
// chunk; per-chunk bucket offsets (ushort) in starts[c*(NB+1) + b].
// ---------------------------------------------------------------------------
__global__ void __launch_bounds__(ABLK)
zbl_phaseA(const int* __restrict__ idx_i, const int* __restrict__ idx_j,
           const float* __restrict__ rij, const float* __restrict__ cut,
           const float* __restrict__ Zf, const float* __restrict__ consts,
           u64* __restrict__ recs, unsigned short* __restrict__ starts,
           int P, int NB) {
    __shared__ unsigned hist[NBMAX];
    __shared__ unsigned scanv[NBMAX];
    __shared__ unsigned cursor[NBMAX];
    __shared__ u64 stage[CHUNK];          // 48 KB

    const int t = threadIdx.x;
    const int c = blockIdx.x;
    const int base = c * CHUNK;
    const int lim = min(base + CHUNK, P);
    const int cnt = lim - base;
    const int n4 = cnt >> 2;

    for (int b = t; b < NBMAX; b += ABLK) hist[b] = 0;
    __syncthreads();

    // ---- pass 1: bucket histogram of this chunk's idx_i
    {
        const v4i* ii4 = reinterpret_cast<const v4i*>(idx_i + base);
        for (int q = t; q < n4; q += ABLK) {
            v4i ii = __builtin_nontemporal_load(ii4 + q);
            atomicAdd(&hist[(unsigned)ii[0] >> APB_SHIFT], 1u);
            atomicAdd(&hist[(unsigned)ii[1] >> APB_SHIFT], 1u);
            atomicAdd(&hist[(unsigned)ii[2] >> APB_SHIFT], 1u);
            atomicAdd(&hist[(unsigned)ii[3] >> APB_SHIFT], 1u);
        }
        for (int p = n4 * 4 + t; p < cnt; p += ABLK)
            atomicAdd(&hist[(unsigned)idx_i[base + p] >> APB_SHIFT], 1u);
    }
    __syncthreads();

    // ---- inclusive Kogge-Stone scan of hist into scanv
    if (t < NBMAX) scanv[t] = hist[t];
    __syncthreads();
    for (int off = 1; off < NBMAX; off <<= 1) {
        unsigned v = 0;
        if (t < NBMAX && t >= off) v = scanv[t - off];
        __syncthreads();
        if (t < NBMAX && t >= off) scanv[t] += v;
        __syncthreads();
    }
    if (t < NBMAX) cursor[t] = scanv[t] - hist[t];   // exclusive base
    // starts row: NB+1 entries of the exclusive scan
    {
        const int S = NB + 1;
        for (int b = t; b <= NB; b += ABLK)
            starts[(size_t)c * S + b] =
                (unsigned short)(b == 0 ? 0u : scanv[b - 1]);
    }
    __syncthreads();

    // ---- pass 2: compute + rank + LDS stage
    const float sp_apow = consts[0], sp_adiv = consts[1];
    const float c1n = consts[2], c2n = consts[3], c3n = consts[4], c4n = consts[5];
    const float a1 = consts[6], a2 = consts[7], a3 = consts[8], a4 = consts[9];

    auto process = [&](int i, int j, float r, float cu) {
        float zfi = Zf[i], zfj = Zf[j];
        float zi = __expf(sp_apow * __logf(zfi));
        float zj = __expf(sp_apow * __logf(zfj));
        float a = (zi + zj) * sp_adiv;
        float ar = a * r;
        float f = c1n * __expf(-a1 * ar) + c2n * __expf(-a2 * ar)
                + c3n * __expf(-a3 * ar) + c4n * __expf(-a4 * ar);
        float contrib = KEHALF * f * cu * zfi * zfj * __builtin_amdgcn_rcpf(r);
        unsigned b = (unsigned)i >> APB_SHIFT;
        unsigned rank = atomicAdd(&cursor[b], 1u);
        stage[rank] = ((u64)((unsigned)i & (APB - 1)) << 32)
                    | (u64)__float_as_uint(contrib);
    };

    {
        const v4i* ii4 = reinterpret_cast<const v4i*>(idx_i + base);
        const v4i* jj4 = reinterpret_cast<const v4i*>(idx_j + base);
        const v4f* rr4 = reinterpret_cast<const v4f*>(rij + base);
        const v4f* cc4 = reinterpret_cast<const v4f*>(cut + base);
        for (int q = t; q < n4; q += ABLK) {
            v4i ii = __builtin_nontemporal_load(ii4 + q);
            v4i jj = __builtin_nontemporal_load(jj4 + q);
            v4f rr = __builtin_nontemporal_load(rr4 + q);
            v4f cc = __builtin_nontemporal_load(cc4 + q);
#pragma unroll
            for (int k = 0; k < 4; ++k) process(ii[k], jj[k], rr[k], cc[k]);
        }
        for (int p = n4 * 4 + t; p < cnt; p += ABLK)
            process(idx_i[base + p], idx_j[base + p], rij[base + p], cut[base + p]);
    }
    __syncthreads();

    // ---- flush: perfectly coalesced streaming stores
    u64* dst = recs + (size_t)base;
    for (int k = t; k < cnt; k += ABLK)
        __builtin_nontemporal_store(stage[k], dst + k);
}

// ---------------------------------------------------------------------------
// Phase B: one block per bucket. Wave-per-chunk segmented read (starts is
// L2-resident), ds-atomic into 8 KB LDS tile, coalesced output store.
// ---------------------------------------------------------------------------
__global__ void __launch_bounds__(BBLK)
zbl_phaseB(const u64* __restrict__ recs,
           const unsigned short* __restrict__ starts,
           float* __restrict__ out, int N, int NB, int nchunks) {
    __shared__ float acc[APB];
    const int t = threadIdx.x;
    const int b = blockIdx.x;
    for (int i = t; i < APB; i += BBLK) acc[i] = 0.f;
    __syncthreads();

    const int S = NB + 1;
    const int wave = t >> 6, lane = t & 63, nw = BBLK / 64;
    for (int c = wave; c < nchunks; c += nw) {
        unsigned s0 = starts[(size_t)c * S + b];
        unsigned s1 = starts[(size_t)c * S + b + 1];
        const u64* seg = recs + (size_t)c * CHUNK;
        for (unsigned u = s0 + lane; u < s1; u += 64) {
            u64 rec = __builtin_nontemporal_load(seg + u);
            atomicAdd(&acc[(unsigned)(rec >> 32)],
                      __uint_as_float((unsigned)rec));
        }
    }
    __syncthreads();

    const int abase = b << APB_SHIFT;
    for (int i = t; i < APB; i += BBLK) {
        int g = abase + i;
        if (g < N) out[g] = acc[i];
    }
}

// ---------------------------------------------------------------------------
// Fallback (tiny ws): direct device-scope atomics.
// ---------------------------------------------------------------------------
__global__ void __launch_bounds__(256)
zbl_pair_fallback(const v4f* __restrict__ rij4, const v4f* __restrict__ cut4,
                  const v4i* __restrict__ ii4, const v4i* __restrict__ jj4,
                  const float* __restrict__ Zf, const float* __restrict__ consts,
                  float* __restrict__ out, int P4) {
    int t = blockIdx.x * blockDim.x + threadIdx.x;
    if (t >= P4) return;
    const float sp_apow = consts[0], sp_adiv = consts[1];
    const float c1n = consts[2], c2n = consts[3], c3n = consts[4], c4n = consts[5];
    const float a1 = consts[6], a2 = consts[7], a3 = consts[8], a4 = consts[9];
    v4f rr = rij4[t]; v4f cc = cut4[t]; v4i ii = ii4[t]; v4i jj = jj4[t];
#pragma unroll
    for (int k = 0; k < 4; ++k) {
        int i = ii[k], j = jj[k];
        float zfi = Zf[i], zfj = Zf[j];
        float zi = __expf(sp_apow * __logf(zfi));
        float zj = __expf(sp_apow * __logf(zfj));
        float a = (zi + zj) * sp_adiv;
        float ar = a * rr[k];
        float f = c1n * __expf(-a1 * ar) + c2n * __expf(-a2 * ar)
                + c3n * __expf(-a3 * ar) + c4n * __expf(-a4 * ar);
        atomicAdd(&out[i],
                  KEHALF * f * cc[k] * zfi * zfj * __builtin_amdgcn_rcpf(rr[k]));
    }
}

// ---------------------------------------------------------------------------
extern "C" void kernel_launch(void* const* d_in, const int* in_sizes, int n_in,
                              void* d_out, int out_size, void* d_ws, size_t ws_size,
                              hipStream_t stream) {
    // 0:N 1:Zf 2:rij 3:cutoff 4:idx_i 5:idx_j 6:adiv 7:apow 8..11:c 12..15:a
    const float* Zf = (const float*)d_in[1];
    const float* rij = (const float*)d_in[2];
    const float* cut = (const float*)d_in[3];
    const int* idx_i = (const int*)d_in[4];
    const int* idx_j = (const int*)d_in[5];
    const int N = in_sizes[1];
    const int P = in_sizes[2];
    float* out = (float*)d_out;

    const int NB = (N + APB - 1) / APB;
    const int nchunks = (P + CHUNK - 1) / CHUNK;

    // ws layout: recs[P] u64 | starts[nchunks*(NB+1)] u16 | consts[16] f32
    size_t recs_bytes = (size_t)P * 8;
    size_t starts_bytes = (size_t)nchunks * (NB + 1) * 2;
    size_t consts_off = (recs_bytes + starts_bytes + 255) & ~(size_t)255;
    size_t need = consts_off + 64;

    if (NB <= NBMAX && ws_size >= need) {
        u64* recs = (u64*)d_ws;
        unsigned short* starts =
            (unsigned short*)((char*)d_ws + recs_bytes);
        float* consts = (float*)((char*)d_ws + consts_off);

        zbl_consts_kernel<<<1, 64, 0, stream>>>(
            (const float*)d_in[6], (const float*)d_in[7],
            (const float*)d_in[8], (const float*)d_in[9],
            (const float*)d_in[10], (const float*)d_in[11],
            (const float*)d_in[12], (const float*)d_in[13],
            (const float*)d_in[14], (const float*)d_in[15], consts);

        zbl_phaseA<<<nchunks, ABLK, 0, stream>>>(
            idx_i, idx_j, rij, cut, Zf, consts, recs, starts, P, NB);

        zbl_phaseB<<<NB, BBLK, 0, stream>>>(recs, starts, out, N, NB, nchunks);
    } else {
        float* consts = (float*)d_ws;
        hipMemsetAsync(out, 0, (size_t)out_size * sizeof(float), stream);
        zbl_consts_kernel<<<1, 64, 0, stream>>>(
            (const float*)d_in[6], (const float*)d_in[7],
            (const float*)d_in[8], (const float*)d_in[9],
            (const float*)d_in[10], (const float*)d_in[11],
            (const float*)d_in[12], (const float*)d_in[13],
            (const float*)d_in[14], (const float*)d_in[15], consts);
        zbl_pair_fallback<<<(P / 4 + 255) / 256, 256, 0, stream>>>(
            (const v4f*)rij, (const v4f*)cut, (const v4i*)idx_i,
            (const v4i*)idx_j, Zf, consts, out, P / 4);
    }
}

// Round 5
// 484.919 us; speedup vs baseline: 2.0359x; 1.0957x over previous
//
#include <hip/hip_runtime.h>
#include <hip/hip_fp16.h>

static constexpr float KEHALF = 7.199822675975274f; // 14.399645351950548 / 2
static constexpr int APB = 2048;          // atoms per bucket (8 KB acc tile)
static constexpr int APB_SHIFT = 11;
static constexpr int NBMAX = 256;         // scan width (pow2); NB <= this
static constexpr int CHUNK = 8192;        // pairs per Phase-A block (32 KB stage)
static constexpr int ABLK = 512;          // Phase-A block size
static constexpr int BBLK = 1024;         // Phase-B block size
static constexpr int CTILE = 2048;        // Phase-B chunk-range staging tile

typedef float v4f __attribute__((ext_vector_type(4)));
typedef int   v4i __attribute__((ext_vector_type(4)));
typedef unsigned v4u __attribute__((ext_vector_type(4)));

// ---------------------------------------------------------------------------
// Tables: consts [0]=sp(apow) [1]=sp(adiv) [2..5]=c1n..c4n [6..9]=sp(a1..a4)
// lutA[v] = sp(adiv) * v^sp(apow)  for v = 0..95  (Zf is an int in 1..94)
// ---------------------------------------------------------------------------
__global__ void zbl_tables_kernel(const float* __restrict__ adiv,
                                  const float* __restrict__ apow,
                                  const float* __restrict__ c1,
                                  const float* __restrict__ c2,
                                  const float* __restrict__ c3,
                                  const float* __restrict__ c4,
                                  const float* __restrict__ a1,
                                  const float* __restrict__ a2,
                                  const float* __restrict__ a3,
                                  const float* __restrict__ a4,
                                  float* __restrict__ consts,
                                  float* __restrict__ lutA) {
    __shared__ float sA[2];
    int t = threadIdx.x;
    if (t == 0) {
        auto sp = [](float x) { return log1pf(expf(x)); };
        float c1p = sp(*c1), c2p = sp(*c2), c3p = sp(*c3), c4p = sp(*c4);
        float inv = 1.0f / (c1p + c2p + c3p + c4p);
        consts[0] = sp(*apow);
        consts[1] = sp(*adiv);
        consts[2] = c1p * inv; consts[3] = c2p * inv;
        consts[4] = c3p * inv; consts[5] = c4p * inv;
        consts[6] = sp(*a1); consts[7] = sp(*a2);
        consts[8] = sp(*a3); consts[9] = sp(*a4);
        sA[0] = consts[0]; sA[1] = consts[1];
    }
    __syncthreads();
    if (t < 96)
        lutA[t] = (t == 0) ? 0.0f : sA[1] * expf(sA[0] * logf((float)t));
}

// ---------------------------------------------------------------------------
// zb[i] = (u8)Zf[i] — 500 KB gather table (fits every XCD's 4 MB L2)
// ---------------------------------------------------------------------------
__global__ void zbl_pack_kernel(const float* __restrict__ Zf,
                                unsigned char* __restrict__ zb, int N) {
    int i = blockIdx.x * blockDim.x + threadIdx.x;
    if (i < N) zb[i] = (unsigned char)(Zf[i] + 0.5f);
}

// ---------------------------------------------------------------------------
// Phase A: per-chunk counting sort. Records are 4 B: [idx_local:16|f16:16].
// LDS ~36 KB -> 4 blocks/CU -> 32 waves/CU. No global atomics.
// ---------------------------------------------------------------------------
__global__ void __launch_bounds__(ABLK)
zbl_phaseA(const int* __restrict__ idx_i, const int* __restrict__ idx_j,
           const float* __restrict__ rij, const float* __restrict__ cut,
           const unsigned char* __restrict__ zb,
           const float* __restrict__ consts, const float* __restrict__ lutA,
           unsigned* __restrict__ recs, unsigned short* __restrict__ starts,
           int P, int NB) {
    __shared__ unsigned hist[NBMAX];
    __shared__ unsigned scanv[NBMAX];
    __shared__ unsigned cursor[NBMAX];
    __shared__ float lA[96];
    __shared__ unsigned stage[CHUNK];     // 32 KB

    const int t = threadIdx.x;
    const int c = blockIdx.x;
    const int base = c * CHUNK;
    const int lim = min(base + CHUNK, P);
    const int cnt = lim - base;
    const int n4 = cnt >> 2;

    for (int b = t; b < NBMAX; b += ABLK) hist[b] = 0;
    if (t < 96) lA[t] = lutA[t];
    __syncthreads();

    // ---- pass 1: bucket histogram of this chunk's idx_i
    {
        const v4i* ii4 = reinterpret_cast<const v4i*>(idx_i + base);
        for (int q = t; q < n4; q += ABLK) {
            v4i ii = __builtin_nontemporal_load(ii4 + q);
            atomicAdd(&hist[(unsigned)ii[0] >> APB_SHIFT], 1u);
            atomicAdd(&hist[(unsigned)ii[1] >> APB_SHIFT], 1u);
            atomicAdd(&hist[(unsigned)ii[2] >> APB_SHIFT], 1u);
            atomicAdd(&hist[(unsigned)ii[3] >> APB_SHIFT], 1u);
        }
        for (int p = n4 * 4 + t; p < cnt; p += ABLK)
            atomicAdd(&hist[(unsigned)idx_i[base + p] >> APB_SHIFT], 1u);
    }
    __syncthreads();

    // ---- inclusive Kogge-Stone scan
    if (t < NBMAX) scanv[t] = hist[t];
    __syncthreads();
    for (int off = 1; off < NBMAX; off <<= 1) {
        unsigned v = 0;
        if (t < NBMAX && t >= off) v = scanv[t - off];
        __syncthreads();
        if (t < NBMAX && t >= off) scanv[t] += v;
        __syncthreads();
    }
    if (t < NBMAX) cursor[t] = scanv[t] - hist[t];   // exclusive base
    {
        const int S = NB + 1;
        for (int b = t; b <= NB; b += ABLK)
            starts[(size_t)c * S + b] =
                (unsigned short)(b == 0 ? 0u : scanv[b - 1]);
    }
    __syncthreads();

    // ---- pass 2: compute + rank + stage
    const float c1n = consts[2], c2n = consts[3], c3n = consts[4], c4n = consts[5];
    const float a1 = consts[6], a2 = consts[7], a3 = consts[8], a4 = consts[9];

    auto process = [&](int i, int j, float r, float cu) {
        unsigned bi = zb[i], bj = zb[j];
        float aij = lA[bi] + lA[bj];
        float ar = aij * r;
        float f = c1n * __expf(-a1 * ar) + c2n * __expf(-a2 * ar)
                + c3n * __expf(-a3 * ar) + c4n * __expf(-a4 * ar);
        float contrib = KEHALF * f * cu * (float)bi * (float)bj *
                        __builtin_amdgcn_rcpf(r);
        unsigned b = (unsigned)i >> APB_SHIFT;
        unsigned rank = atomicAdd(&cursor[b], 1u);
        stage[rank] = (((unsigned)i & (APB - 1)) << 16)
                    | (unsigned)__half_as_ushort(__float2half_rn(contrib));
    };

    {
        const v4i* ii4 = reinterpret_cast<const v4i*>(idx_i + base);
        const v4i* jj4 = reinterpret_cast<const v4i*>(idx_j + base);
        const v4f* rr4 = reinterpret_cast<const v4f*>(rij + base);
        const v4f* cc4 = reinterpret_cast<const v4f*>(cut + base);
        for (int q = t; q < n4; q += ABLK) {
            v4i ii = __builtin_nontemporal_load(ii4 + q);
            v4i jj = __builtin_nontemporal_load(jj4 + q);
            v4f rr = __builtin_nontemporal_load(rr4 + q);
            v4f cc = __builtin_nontemporal_load(cc4 + q);
#pragma unroll
            for (int k = 0; k < 4; ++k) process(ii[k], jj[k], rr[k], cc[k]);
        }
        for (int p = n4 * 4 + t; p < cnt; p += ABLK)
            process(idx_i[base + p], idx_j[base + p], rij[base + p], cut[base + p]);
    }
    __syncthreads();

    // ---- flush: coalesced 16 B/lane streaming stores (full chunk; pad
    // entries beyond cnt are garbage but never referenced by starts)
    {
        const v4u* src = reinterpret_cast<const v4u*>(stage);
        v4u* dst = reinterpret_cast<v4u*>(recs + (size_t)base);
        for (int k = t; k < CHUNK / 4; k += ABLK)
            __builtin_nontemporal_store(src[k], dst + k);
    }
}

// ---------------------------------------------------------------------------
// Phase B: one block per bucket. Chunk-range staging in LDS (breaks the
// dependent starts->records chain), ds-atomic into 8 KB tile, coalesced out.
// ---------------------------------------------------------------------------
__global__ void __launch_bounds__(BBLK)
zbl_phaseB(const unsigned* __restrict__ recs,
           const unsigned short* __restrict__ starts,
           float* __restrict__ out, int N, int NB, int nchunks) {
    __shared__ float acc[APB];                 // 8 KB
    __shared__ unsigned short s0s[CTILE];      // 4 KB
    __shared__ unsigned short s1s[CTILE];      // 4 KB
    const int t = threadIdx.x;
    const int b = blockIdx.x;
    const int S = NB + 1;
    for (int i = t; i < APB; i += BBLK) acc[i] = 0.f;

    const int wave = t >> 6, lane = t & 63, nw = BBLK / 64;

    for (int cb = 0; cb < nchunks; cb += CTILE) {
        const int ce = min(cb + CTILE, nchunks);
        __syncthreads();
        for (int c = cb + t; c < ce; c += BBLK) {
            s0s[c - cb] = starts[(size_t)c * S + b];
            s1s[c - cb] = starts[(size_t)c * S + b + 1];
        }
        __syncthreads();
        for (int c = cb + wave; c < ce; c += nw) {
            unsigned s0 = s0s[c - cb], s1 = s1s[c - cb];
            const unsigned* seg = recs + (size_t)c * CHUNK;
            for (unsigned u = s0 + lane; u < s1; u += 64) {
                unsigned rec = __builtin_nontemporal_load(seg + u);
                float v = __half2float(__ushort_as_half((unsigned short)(rec & 0xffffu)));
                atomicAdd(&acc[rec >> 16], v);
            }
        }
    }
    __syncthreads();

    const int abase = b << APB_SHIFT;
    for (int i = t; i < APB; i += BBLK) {
        int g = abase + i;
        if (g < N) out[g] = acc[i];
    }
}

// ---------------------------------------------------------------------------
// Fallback (tiny ws): direct device-scope atomics.
// ---------------------------------------------------------------------------
__global__ void __launch_bounds__(256)
zbl_pair_fallback(const v4f* __restrict__ rij4, const v4f* __restrict__ cut4,
                  const v4i* __restrict__ ii4, const v4i* __restrict__ jj4,
                  const float* __restrict__ Zf, const float* __restrict__ consts,
                  float* __restrict__ out, int P4) {
    int t = blockIdx.x * blockDim.x + threadIdx.x;
    if (t >= P4) return;
    const float sp_apow = consts[0], sp_adiv = consts[1];
    const float c1n = consts[2], c2n = consts[3], c3n = consts[4], c4n = consts[5];
    const float a1 = consts[6], a2 = consts[7], a3 = consts[8], a4 = consts[9];
    v4f rr = rij4[t]; v4f cc = cut4[t]; v4i ii = ii4[t]; v4i jj = jj4[t];
#pragma unroll
    for (int k = 0; k < 4; ++k) {
        int i = ii[k], j = jj[k];
        float zfi = Zf[i], zfj = Zf[j];
        float zi = __expf(sp_apow * __logf(zfi));
        float zj = __expf(sp_apow * __logf(zfj));
        float a = (zi + zj) * sp_adiv;
        float ar = a * rr[k];
        float f = c1n * __expf(-a1 * ar) + c2n * __expf(-a2 * ar)
                + c3n * __expf(-a3 * ar) + c4n * __expf(-a4 * ar);
        atomicAdd(&out[i],
                  KEHALF * f * cc[k] * zfi * zfj * __builtin_amdgcn_rcpf(rr[k]));
    }
}

// ---------------------------------------------------------------------------
extern "C" void kernel_launch(void* const* d_in, const int* in_sizes, int n_in,
                              void* d_out, int out_size, void* d_ws, size_t ws_size,
                              hipStream_t stream) {
    // 0:N 1:Zf 2:rij 3:cutoff 4:idx_i 5:idx_j 6:adiv 7:apow 8..11:c 12..15:a
    const float* Zf = (const float*)d_in[1];
    const float* rij = (const float*)d_in[2];
    const float* cut = (const float*)d_in[3];
    const int* idx_i = (const int*)d_in[4];
    const int* idx_j = (const int*)d_in[5];
    const int N = in_sizes[1];
    const int P = in_sizes[2];
    float* out = (float*)d_out;

    const int NB = (N + APB - 1) / APB;
    const int nchunks = (P + CHUNK - 1) / CHUNK;

    // ws layout: recs[nchunks*CHUNK] u32 | starts[nchunks*(NB+1)] u16 |
    //            consts[16] f32 | lutA[96] f32 | zb[N] u8
    size_t recs_bytes = (size_t)nchunks * CHUNK * 4;
    size_t starts_bytes = (size_t)nchunks * (NB + 1) * 2;
    size_t consts_off = (recs_bytes + starts_bytes + 255) & ~(size_t)255;
    size_t lut_off = consts_off + 16 * 4;
    size_t zb_off = lut_off + 96 * 4;
    size_t need = zb_off + (size_t)N + 64;

    if (NB <= NBMAX && ws_size >= need) {
        unsigned* recs = (unsigned*)d_ws;
        unsigned short* starts = (unsigned short*)((char*)d_ws + recs_bytes);
        float* consts = (float*)((char*)d_ws + consts_off);
        float* lutA = (float*)((char*)d_ws + lut_off);
        unsigned char* zb = (unsigned char*)((char*)d_ws + zb_off);

        zbl_tables_kernel<<<1, 128, 0, stream>>>(
            (const float*)d_in[6], (const float*)d_in[7],
            (const float*)d_in[8], (const float*)d_in[9],
            (const float*)d_in[10], (const float*)d_in[11],
            (const float*)d_in[12], (const float*)d_in[13],
            (const float*)d_in[14], (const float*)d_in[15], consts, lutA);

        zbl_pack_kernel<<<(N + 255) / 256, 256, 0, stream>>>(Zf, zb, N);

        zbl_phaseA<<<nchunks, ABLK, 0, stream>>>(
            idx_i, idx_j, rij, cut, zb, consts, lutA, recs, starts, P, NB);

        zbl_phaseB<<<NB, BBLK, 0, stream>>>(recs, starts, out, N, NB, nchunks);
    } else {
        float* consts = (float*)d_ws;
        float* lutA = consts + 16;
        hipMemsetAsync(out, 0, (size_t)out_size * sizeof(float), stream);
        zbl_tables_kernel<<<1, 128, 0, stream>>>(
            (const float*)d_in[6], (const float*)d_in[7],
            (const float*)d_in[8], (const float*)d_in[9],
            (const float*)d_in[10], (const float*)d_in[11],
            (const float*)d_in[12], (const float*)d_in[13],
            (const float*)d_in[14], (const float*)d_in[15], consts, lutA);
        zbl_pair_fallback<<<(P / 4 + 255) / 256, 256, 0, stream>>>(
            (const v4f*)rij, (const v4f*)cut, (const v4i*)idx_i,
            (const v4i*)idx_j, Zf, consts, out, P / 4);
    }
}